// Round 8
// baseline (32.650 us; speedup 1.0000x reference)
//
#include <hip/hip_runtime.h>

// BipartPool fused: GATv2 bipartite pooling, fully-regular structure.
// lrelu(z) = 0.6z + 0.4|z| -> logit = dot(xl,att6) + xr_att6[r,h] + sum_c |xl+xr|*att4
// No-max softmax (logits ~N(0,1), f32 exp safe): alpha = ex/den; den divided out in k2;
// PV runs on unnormalized ex; den comes free as a ones-column MFMA.
// 3 launches (fused finalize w/ __threadfence = L2 wbl2/inv storm on 8 XCDs; reverted R6).
// k1: 512 blocks x 512 threads, 8 waves role-split: wave=(h, half).
//   half = mh (phase B: M-split) = rhalf (phase D: r-split -> xr stream is a wave-uniform
//   s_load_dwordx8, 8 SGPR/iter -> pipelines deep) = ehalf (phase E: N-split).
//   LDS: stride-64 shorts + XOR-swizzle on 16B units (col_unit ^= row&7), 40960 B total
//   -> 2 blocks/CU (82KB), 16 waves/CU = 4 waves/SIMD (2x R7's grid-capped 2).

typedef __attribute__((ext_vector_type(8))) short short8;
typedef __attribute__((ext_vector_type(4))) float f32x4;

#define NPG 1024
#define NT 512

static __device__ __forceinline__ unsigned short f2bf(float f) {
    unsigned int u = __float_as_uint(f);
    u += 0x7fffu + ((u >> 16) & 1u);        // RNE (data is normal, no NaN handling)
    return (unsigned short)(u >> 16);
}
static __device__ __forceinline__ float bf2f(unsigned short u) {
    return __uint_as_float(((unsigned int)u) << 16);
}
// swizzled column (shorts): unit = 8 shorts (16B). col8 must be the unit index.
static __device__ __forceinline__ int swz(int row, int unit) { return (unit ^ (row & 7)) << 3; }

// ---------------- K0: tables xrT[hc][16r], xr_att6, att6/att4, Wt bf16; batchcent --------
__global__ __launch_bounds__(256) void k0_prep(const float* __restrict__ xcb,
                                               const float* __restrict__ W_l,
                                               const float* __restrict__ W_r,
                                               const float* __restrict__ b_r,
                                               const float* __restrict__ att,
                                               float* __restrict__ xrT,
                                               float* __restrict__ xr_att6,
                                               float* __restrict__ att6,
                                               float* __restrict__ att4,
                                               unsigned short* __restrict__ wt,
                                               float* __restrict__ out) {
    int b = blockIdx.x, t = threadIdx.x;
    if (b < 16) {
        int r = b, hc = t;                  // one wave per head; W_r coalesced over hc
        float v = b_r[hc];
#pragma unroll
        for (int k = 0; k < 64; ++k)
            v = fmaf(xcb[r * 64 + k], W_r[k * 256 + hc], v);
        xrT[hc * 16 + r] = v;               // [hc][16r]: k1 s_loads 8-r half-rows
        float p = 0.6f * att[hc] * v;
        p += __shfl_xor(p, 1);  p += __shfl_xor(p, 2);
        p += __shfl_xor(p, 4);  p += __shfl_xor(p, 8);
        p += __shfl_xor(p, 16); p += __shfl_xor(p, 32);
        if ((t & 63) == 0) xr_att6[r * 4 + (t >> 6)] = p;
    } else {
        att6[t] = 0.6f * att[t];
        att4[t] = 0.4f * att[t];
        // Wt[c][k] = bf16(W_l[k][c])  (k-contiguous for MFMA B-frags)
        unsigned short tmp[64] __attribute__((aligned(16)));
#pragma unroll
        for (int k = 0; k < 64; ++k) tmp[k] = f2bf(W_l[k * 256 + t]);
#pragma unroll
        for (int q = 0; q < 8; ++q)
            *(short8*)(wt + t * 64 + q * 8) = *(const short8*)(tmp + q * 8);
        // batchcent: input-independent
        out[NT * 64 + t]       = (float)(t >> 4);
        out[NT * 64 + 256 + t] = (float)((256 + t) >> 4);
    }
}

// ---------------- K1: fused xl -> logits -> ex -> PV bf16 partials (8 waves) -------------
__global__ __launch_bounds__(512, 4) void k1_fused(const float* __restrict__ x,
                                                   const unsigned short* __restrict__ wt,
                                                   const float* __restrict__ b_l,
                                                   const float* __restrict__ att6,
                                                   const float* __restrict__ att4,
                                                   const float* __restrict__ xrT,
                                                   const float* __restrict__ xr_att6,
                                                   unsigned short* __restrict__ ws_pvh,
                                                   float* __restrict__ ws_denp) {
    // X: rows 0..63 = As (x tile, bf16), then all 256 rows = xlT[hc][n]; E: exT[h*16+r][n].
    // All stride 64 shorts (128B), XOR-swizzled on 16B units with row&7.
    __shared__ __align__(16) short LL[320][64];   // 40960 B exactly
    short (*X)[64] = LL;
    short (*E)[64] = LL + 256;

    const int t = threadIdx.x;
    const int blk = blockIdx.x;              // 512 tiles of 64 nodes
    const int n0 = blk * 64;

    // ---- phase A: stage x[64n][64k] f32 -> bf16 X[0..63] (swizzled) ----
    {
        int n = t >> 3, u = t & 7;           // 8 threads per node, one 16B unit each
        const float* p = x + (size_t)(n0 + n) * 64 + u * 8;
        float4 v0 = *(const float4*)p;
        float4 v1 = *(const float4*)(p + 4);
        unsigned short h8[8] __attribute__((aligned(16)));
        h8[0]=f2bf(v0.x); h8[1]=f2bf(v0.y); h8[2]=f2bf(v0.z); h8[3]=f2bf(v0.w);
        h8[4]=f2bf(v1.x); h8[5]=f2bf(v1.y); h8[6]=f2bf(v1.z); h8[7]=f2bf(v1.w);
        *(short8*)(&X[n][swz(n, u)]) = *(const short8*)h8;
    }
    __syncthreads();

    const int l = t & 63;
    const int w = t >> 6;
    const int h    = __builtin_amdgcn_readfirstlane(w & 3);   // head
    const int half = __builtin_amdgcn_readfirstlane(w >> 2);  // role split (M / r / N)
    const int lm = l & 15, lq = l >> 4;      // lq in 0..3; lk = lq*8

    // ---- phase B: MFMA C[64n][64c] = x @ W_l(head h); this wave: m-half = half ----
    short8 af[2][2], bfr[4][2];
#pragma unroll
    for (int mt = 0; mt < 2; ++mt)
#pragma unroll
        for (int ks = 0; ks < 2; ++ks) {
            int row = half * 32 + mt * 16 + lm;
            af[mt][ks] = *(const short8*)(&X[row][swz(row, ks * 4 + lq)]);
        }
#pragma unroll
    for (int nt = 0; nt < 4; ++nt)
#pragma unroll
        for (int ks = 0; ks < 2; ++ks)
            bfr[nt][ks] = *(const short8*)(wt + (size_t)(h * 64 + nt * 16 + lm) * 64 + ks * 32 + lq * 8);

    f32x4 acc[2][4];
#pragma unroll
    for (int mt = 0; mt < 2; ++mt)
#pragma unroll
        for (int nt = 0; nt < 4; ++nt) { f32x4 z = {0.f,0.f,0.f,0.f}; acc[mt][nt] = z; }
#pragma unroll
    for (int mt = 0; mt < 2; ++mt)
#pragma unroll
        for (int nt = 0; nt < 4; ++nt)
#pragma unroll
            for (int ks = 0; ks < 2; ++ks)
                acc[mt][nt] = __builtin_amdgcn_mfma_f32_16x16x32_bf16(
                    af[mt][ks], bfr[nt][ks], acc[mt][nt], 0, 0, 0);

    __syncthreads();   // all waves done reading As; xlT overwrites X

    // ---- phase C: acc(+b_l) -> X[h*64+c][n] bf16 (swizzled) ----
    // C layout: col(c) = lm (+nt*16), row(n) = lq*4 + j (+mt*16 + half*32)  [m89-verified]
#pragma unroll
    for (int nt = 0; nt < 4; ++nt) {
        float bl = b_l[h * 64 + nt * 16 + lm];
#pragma unroll
        for (int mt = 0; mt < 2; ++mt) {
            unsigned int d0 = (unsigned int)f2bf(acc[mt][nt][0] + bl) |
                              ((unsigned int)f2bf(acc[mt][nt][1] + bl) << 16);
            unsigned int d1 = (unsigned int)f2bf(acc[mt][nt][2] + bl) |
                              ((unsigned int)f2bf(acc[mt][nt][3] + bl) << 16);
            int row = h * 64 + nt * 16 + lm;
            int ncol = half * 32 + mt * 16 + lq * 4;          // 4-short aligned
            int col = swz(row, ncol >> 3) + (ncol & 7);
            *(uint2*)(&X[row][col]) = make_uint2(d0, d1);
        }
    }
    __syncthreads();

    // ---- phase D: logits for r in [half*8, half*8+8); xr half-rows = s_load_dwordx8 ----
    float base = 0.f;
    float lacc[8];
#pragma unroll
    for (int rr = 0; rr < 8; ++rr) lacc[rr] = 0.f;
#pragma unroll 4
    for (int c = 0; c < 64; ++c) {
        int row = h * 64 + c;
        float xv = bf2f((unsigned short)X[row][swz(row, l >> 3) + (l & 7)]);
        base = fmaf(xv, att6[row], base);
        float a4 = att4[row];
        const float* xp = xrT + (size_t)row * 16 + half * 8;  // wave-uniform: s_load x8
#pragma unroll
        for (int rr = 0; rr < 8; ++rr)
            lacc[rr] = fmaf(fabsf(xv + xp[rr]), a4, lacc[rr]);  // abs = free VOP3 modifier
    }
#pragma unroll
    for (int rr = 0; rr < 8; ++rr) {
        int r = half * 8 + rr;
        float ex = __expf(base + lacc[rr] + xr_att6[r * 4 + h]);   // no-max softmax
        int erow = h * 16 + r;
        E[erow][swz(erow, l >> 3) + (l & 7)] = (short)f2bf(ex);
    }
    __syncthreads();

    // ---- phase E: PV MFMA: pacc[16r][64c] = ex^T @ xl; this wave: nt = half*2 + {0,1} ----
    short8 ap[2];
#pragma unroll
    for (int ks = 0; ks < 2; ++ks) {
        int erow = h * 16 + lm;
        ap[ks] = *(const short8*)(&E[erow][swz(erow, ks * 4 + lq)]);
    }
    f32x4 pacc[2], dacc;
    { f32x4 z = {0.f,0.f,0.f,0.f}; pacc[0]=z; pacc[1]=z; dacc=z; }
#pragma unroll
    for (int ks = 0; ks < 2; ++ks) {
#pragma unroll
        for (int ntl = 0; ntl < 2; ++ntl) {
            int row = h * 64 + (half * 2 + ntl) * 16 + lm;
            short8 bp = *(const short8*)(&X[row][swz(row, ks * 4 + lq)]);
            pacc[ntl] = __builtin_amdgcn_mfma_f32_16x16x32_bf16(ap[ks], bp, pacc[ntl], 0, 0, 0);
        }
        if (half == 0) {
            short o = (lm == 0) ? (short)0x3F80 : (short)0;   // bf16 1.0 in column 0
            short8 onesf = {o, o, o, o, o, o, o, o};
            dacc = __builtin_amdgcn_mfma_f32_16x16x32_bf16(ap[ks], onesf, dacc, 0, 0, 0);
        }
    }

    // ---- store partials: pvh[blk][h][16r][64c] bf16, denp[blk][h][16r] f32 ----
    unsigned short* pvb = ws_pvh + ((size_t)blk * 4 + h) * 1024;
#pragma unroll
    for (int ntl = 0; ntl < 2; ++ntl)
#pragma unroll
        for (int j = 0; j < 4; ++j)
            pvb[(lq * 4 + j) * 64 + (half * 2 + ntl) * 16 + lm] = f2bf(pacc[ntl][j]);
    if (half == 0 && lm == 0) {
#pragma unroll
        for (int j = 0; j < 4; ++j)
            ws_denp[((size_t)blk * 4 + h) * 16 + lq * 4 + j] = dacc[j];
    }
}

// ---------------- K2: reduce 16 tiles: out = 0.25*sum_h num/den + bias ------------------
__global__ __launch_bounds__(256) void k2_final(const unsigned short* __restrict__ ws_pvh,
                                                const float* __restrict__ ws_denp,
                                                const float* __restrict__ bias,
                                                float* __restrict__ out) {
    int b = blockIdx.x;                         // 128 = g(32) x rquad(4)
    int g = b >> 2;
    int r = (b & 3) * 4 + (threadIdx.x >> 6);   // wave-uniform -> den via s_loads
    int c = threadIdx.x & 63;
    float acc = 0.f;
#pragma unroll
    for (int h = 0; h < 4; ++h) {
        float num = 0.f, den = 0.f;
#pragma unroll
        for (int tl = 0; tl < 16; ++tl) {
            num += bf2f(ws_pvh[(((size_t)(g * 16 + tl)) * 4 + h) * 1024 + r * 64 + c]);
            den += ws_denp[((size_t)(g * 16 + tl) * 4 + h) * 16 + r];
        }
        acc += num / den;
    }
    out[(size_t)(g * 16 + r) * 64 + c] = fmaf(0.25f, acc, bias[c]);
}

extern "C" void kernel_launch(void* const* d_in, const int* in_sizes, int n_in,
                              void* d_out, int out_size, void* d_ws, size_t ws_size,
                              hipStream_t stream) {
    const float* x    = (const float*)d_in[0];
    const float* xcb  = (const float*)d_in[3];
    const float* W_l  = (const float*)d_in[4];
    const float* b_l  = (const float*)d_in[5];
    const float* W_r  = (const float*)d_in[6];
    const float* b_r  = (const float*)d_in[7];
    const float* att  = (const float*)d_in[8];
    const float* bias = (const float*)d_in[9];
    float* out = (float*)d_out;

    // workspace layout (~4.3 MB)
    unsigned short* ws_pvh = (unsigned short*)d_ws;       // 512 blk x 4 h x 16 r x 64 c bf16
    float* ws_denp = (float*)(ws_pvh + 2097152);          // 512 x 4 x 16 f32
    float* xrT     = ws_denp + 32768;                     // [hc][16r]
    float* xr_att6 = xrT + 4096;                          // 64
    float* att6    = xr_att6 + 64;                        // 256
    float* att4    = att6 + 256;                          // 256
    unsigned short* wt = (unsigned short*)(att4 + 256);   // 256x64 bf16

    k0_prep<<<17, 256, 0, stream>>>(xcb, W_l, W_r, b_r, att, xrT, xr_att6, att6, att4, wt, out);
    k1_fused<<<512, 512, 0, stream>>>(x, wt, b_l, att6, att4, xrT, xr_att6, ws_pvh, ws_denp);
    k2_final<<<128, 256, 0, stream>>>(ws_pvh, ws_denp, bias, out);
}

// Round 10
// 32.237 us; speedup vs baseline: 1.0128x; 1.0128x over previous
//
#include <hip/hip_runtime.h>

// BipartPool fused: GATv2 bipartite pooling, fully-regular structure.
// lrelu(z) = 0.6z + 0.4|z| -> logit = dot(xl,att6) + xr_att6[r,h] + sum_c |xl+xr|*att4
// No-max softmax (logits ~N(0,1), f32 exp safe): alpha = ex/den; den divided out in k2;
// PV runs on unnormalized ex; den comes free as a ones-column MFMA.
// R9 post-mortem: removing the C->D / D->E barriers raced. Phase C writes LDS via
// uint2*, phase D reads the same bytes via short* -- TBAA says no alias, so the compiler
// may reorder the reads above the writes. __syncthreads() is the IR-level fence that
// makes the mixed-type LDS reuse legal. Barriers restored (4 total; measured cost ~0).
// New probe: xr table moved to LDS (XR4) -- phase D's per-c xr row read becomes 4x
// ds_read_b128 at a wave-uniform (broadcast) address instead of s_load_dwordx16 streams
// whose prefetch depth is SGPR-capped.

typedef __attribute__((ext_vector_type(8))) short short8;
typedef __attribute__((ext_vector_type(4))) float f32x4;

#define NPG 1024
#define NT 512

// f32 -> bf16 via HW packed convert (no builtin on gfx950; inline asm, RNE)
static __device__ __forceinline__ unsigned int cvt2(float lo, float hi) {
    unsigned int r;
    asm("v_cvt_pk_bf16_f32 %0, %1, %2" : "=v"(r) : "v"(lo), "v"(hi));
    return r;
}
static __device__ __forceinline__ unsigned short f2bf(float f) {
    unsigned int r;
    asm("v_cvt_pk_bf16_f32 %0, %1, %1" : "=v"(r) : "v"(f));
    return (unsigned short)r;
}
static __device__ __forceinline__ float bf2f(unsigned short u) {
    return __uint_as_float(((unsigned int)u) << 16);
}
// swizzled column (shorts): unit = 8 shorts (16B); involution col_unit ^= row&7
static __device__ __forceinline__ int swz(int row, int unit) { return (unit ^ (row & 7)) << 3; }

// ---------------- K0: tables xrT[hc][16r], xr_att6, att6/att4, Wt bf16; batchcent --------
__global__ __launch_bounds__(256) void k0_prep(const float* __restrict__ xcb,
                                               const float* __restrict__ W_l,
                                               const float* __restrict__ W_r,
                                               const float* __restrict__ b_r,
                                               const float* __restrict__ att,
                                               float* __restrict__ xrT,
                                               float* __restrict__ xr_att6,
                                               float* __restrict__ att6,
                                               float* __restrict__ att4,
                                               unsigned short* __restrict__ wt,
                                               float* __restrict__ out) {
    int b = blockIdx.x, t = threadIdx.x;
    if (b < 16) {
        int r = b, hc = t;                  // one wave per head; W_r coalesced over hc
        float v = b_r[hc];
#pragma unroll
        for (int k = 0; k < 64; ++k)
            v = fmaf(xcb[r * 64 + k], W_r[k * 256 + hc], v);
        xrT[hc * 16 + r] = v;               // [hc][16r]: k1 stages this into LDS
        float p = 0.6f * att[hc] * v;
        p += __shfl_xor(p, 1);  p += __shfl_xor(p, 2);
        p += __shfl_xor(p, 4);  p += __shfl_xor(p, 8);
        p += __shfl_xor(p, 16); p += __shfl_xor(p, 32);
        if ((t & 63) == 0) xr_att6[r * 4 + (t >> 6)] = p;
    } else {
        att6[t] = 0.6f * att[t];
        att4[t] = 0.4f * att[t];
        // Wt[c][k] = bf16(W_l[k][c])  (k-contiguous for MFMA B-frags)
        unsigned int tmp[32] __attribute__((aligned(16)));
#pragma unroll
        for (int k = 0; k < 32; ++k)
            tmp[k] = cvt2(W_l[(2 * k) * 256 + t], W_l[(2 * k + 1) * 256 + t]);
#pragma unroll
        for (int q = 0; q < 8; ++q)
            *(uint4*)(wt + t * 64 + q * 8) = *(const uint4*)(tmp + q * 4);
        // batchcent: input-independent
        out[NT * 64 + t]       = (float)(t >> 4);
        out[NT * 64 + 256 + t] = (float)((256 + t) >> 4);
    }
}

// ---------------- K1: fused xl -> logits -> ex -> PV bf16 partials (wave = head) ---------
__global__ __launch_bounds__(256, 2) void k1_fused(const float* __restrict__ x,
                                                   const unsigned short* __restrict__ wt,
                                                   const float* __restrict__ b_l,
                                                   const float* __restrict__ att6,
                                                   const float* __restrict__ att4,
                                                   const float* __restrict__ xrT,
                                                   const float* __restrict__ xr_att6,
                                                   unsigned short* __restrict__ ws_pvh,
                                                   float* __restrict__ ws_denp) {
    // X rows 0..63 = staged x tile (aliases xlT head 0); X all rows = xlT[hc][n];
    // E = exT[h*16+r][n]. Stride 64 shorts, XOR-swizzled 16B units. 40960 B.
    // XR4[hc][16r] f32 = xr table (16 KB): phase-D reads are wave-uniform broadcasts.
    __shared__ __align__(16) short LL[320][64];
    __shared__ __align__(16) float XR4[256][16];
    short (*X)[64] = LL;
    short (*E)[64] = LL + 256;

    const int t = threadIdx.x;
    const int blk = blockIdx.x;              // 512 tiles of 64 nodes
    const int n0 = blk * 64;

    // ---- phase A: stage x[64n][64k] f32 -> bf16 X[0..63] (swizzled); stage XR4 ----
    {
        int n = t >> 2, u0 = (t & 3) * 2;    // 4 threads/node, 2 units (16 shorts) each
        const float* p = x + (size_t)(n0 + n) * 64 + u0 * 8;
        float4 v0 = *(const float4*)p;
        float4 v1 = *(const float4*)(p + 4);
        float4 v2 = *(const float4*)(p + 8);
        float4 v3 = *(const float4*)(p + 12);
        uint4 a, b;
        a.x = cvt2(v0.x, v0.y); a.y = cvt2(v0.z, v0.w);
        a.z = cvt2(v1.x, v1.y); a.w = cvt2(v1.z, v1.w);
        b.x = cvt2(v2.x, v2.y); b.y = cvt2(v2.z, v2.w);
        b.z = cvt2(v3.x, v3.y); b.w = cvt2(v3.z, v3.w);
        *(uint4*)(&X[n][swz(n, u0)])     = a;
        *(uint4*)(&X[n][swz(n, u0 + 1)]) = b;
        // xr table: thread t copies row t (16 f32 = 64 B)
        const float4* xr = (const float4*)(xrT + t * 16);
        float4 r0 = xr[0], r1 = xr[1], r2 = xr[2], r3 = xr[3];
        float4* xd = (float4*)(&XR4[t][0]);
        xd[0] = r0; xd[1] = r1; xd[2] = r2; xd[3] = r3;
    }
    __syncthreads();                         // barrier 1: staged tiles visible

    const int l = t & 63;
    const int h = __builtin_amdgcn_readfirstlane(t >> 6);   // wave = head
    const int lm = l & 15, lq = l >> 4;

    // ---- phase B: MFMA C[64n][64c] = x @ W_l(head h) ----
    short8 af[4][2], bfr[4][2];
#pragma unroll
    for (int mt = 0; mt < 4; ++mt)
#pragma unroll
        for (int ks = 0; ks < 2; ++ks) {
            int row = mt * 16 + lm;
            af[mt][ks] = *(const short8*)(&X[row][swz(row, ks * 4 + lq)]);
        }
#pragma unroll
    for (int nt = 0; nt < 4; ++nt)
#pragma unroll
        for (int ks = 0; ks < 2; ++ks)
            bfr[nt][ks] = *(const short8*)(wt + (size_t)(h * 64 + nt * 16 + lm) * 64 + ks * 32 + lq * 8);

    f32x4 acc[4][4];
#pragma unroll
    for (int mt = 0; mt < 4; ++mt)
#pragma unroll
        for (int nt = 0; nt < 4; ++nt) { f32x4 z = {0.f,0.f,0.f,0.f}; acc[mt][nt] = z; }
#pragma unroll
    for (int mt = 0; mt < 4; ++mt)
#pragma unroll
        for (int nt = 0; nt < 4; ++nt)
#pragma unroll
            for (int ks = 0; ks < 2; ++ks)
                acc[mt][nt] = __builtin_amdgcn_mfma_f32_16x16x32_bf16(
                    af[mt][ks], bfr[nt][ks], acc[mt][nt], 0, 0, 0);

    __syncthreads();   // barrier 2: all frag reads done; xlT may overwrite x tile

    // ---- phase C: acc(+b_l) -> X[h*64+c][n] bf16 (swizzled) ----
    // C layout: col(c) = lm (+nt*16), row(n) = lq*4 + j (+mt*16)   [m89-verified]
#pragma unroll
    for (int nt = 0; nt < 4; ++nt) {
        float bl = b_l[h * 64 + nt * 16 + lm];
#pragma unroll
        for (int mt = 0; mt < 4; ++mt) {
            unsigned int d0 = cvt2(acc[mt][nt][0] + bl, acc[mt][nt][1] + bl);
            unsigned int d1 = cvt2(acc[mt][nt][2] + bl, acc[mt][nt][3] + bl);
            int row = h * 64 + nt * 16 + lm;
            int ncol = mt * 16 + lq * 4;                      // 4-short aligned
            int col = swz(row, ncol >> 3) + (ncol & 7);
            *(uint2*)(&X[row][col]) = make_uint2(d0, d1);
        }
    }
    __syncthreads();   // barrier 3: fence the uint2 stores vs phase-D short reads (TBAA)

    // ---- phase D: logits; xv from own rows; xr rows = LDS broadcast ds_read_b128 ----
    float base = 0.f;
    float lacc[16];
#pragma unroll
    for (int r = 0; r < 16; ++r) lacc[r] = 0.f;
#pragma unroll 4
    for (int c = 0; c < 64; ++c) {
        int row = h * 64 + c;
        float xv = bf2f((unsigned short)X[row][swz(row, l >> 3) + (l & 7)]);
        base = fmaf(xv, att6[row], base);
        float a4 = att4[row];
        float xr4v[16];
        const float4* xp = (const float4*)(&XR4[row][0]);     // wave-uniform -> broadcast
        *(float4*)(xr4v + 0)  = xp[0];
        *(float4*)(xr4v + 4)  = xp[1];
        *(float4*)(xr4v + 8)  = xp[2];
        *(float4*)(xr4v + 12) = xp[3];
#pragma unroll
        for (int r = 0; r < 16; ++r)
            lacc[r] = fmaf(fabsf(xv + xr4v[r]), a4, lacc[r]); // abs = free VOP3 modifier
    }
#pragma unroll
    for (int r = 0; r < 16; ++r) {
        float ex = __expf(base + lacc[r] + xr_att6[r * 4 + h]);   // no-max softmax
        int erow = h * 16 + r;
        E[erow][swz(erow, l >> 3) + (l & 7)] = (short)f2bf(ex);
    }
    __syncthreads();   // barrier 4: fence E scalar stores vs phase-E short8 reads

    // ---- phase E: PV MFMA: pacc[16r][64c] = ex^T @ xl ; ones-col B gives den ----
    short8 ap[2];
#pragma unroll
    for (int ks = 0; ks < 2; ++ks) {
        int erow = h * 16 + lm;
        ap[ks] = *(const short8*)(&E[erow][swz(erow, ks * 4 + lq)]);
    }
    short o = (lm == 0) ? (short)0x3F80 : (short)0;   // bf16 1.0 in column 0
    short8 onesf = {o, o, o, o, o, o, o, o};

    f32x4 pacc[4], dacc;
    { f32x4 z = {0.f,0.f,0.f,0.f}; pacc[0]=z; pacc[1]=z; pacc[2]=z; pacc[3]=z; dacc=z; }
#pragma unroll
    for (int ks = 0; ks < 2; ++ks) {
#pragma unroll
        for (int nt = 0; nt < 4; ++nt) {
            int row = h * 64 + nt * 16 + lm;
            short8 bp = *(const short8*)(&X[row][swz(row, ks * 4 + lq)]);
            pacc[nt] = __builtin_amdgcn_mfma_f32_16x16x32_bf16(ap[ks], bp, pacc[nt], 0, 0, 0);
        }
        dacc = __builtin_amdgcn_mfma_f32_16x16x32_bf16(ap[ks], onesf, dacc, 0, 0, 0);
    }

    // ---- store partials: pvh[blk][h][16r][64c] bf16, denp[blk][h][16r] f32 ----
    unsigned short* pvb = ws_pvh + ((size_t)blk * 4 + h) * 1024;
#pragma unroll
    for (int nt = 0; nt < 4; ++nt)
#pragma unroll
        for (int j = 0; j < 4; ++j)
            pvb[(lq * 4 + j) * 64 + nt * 16 + lm] = f2bf(pacc[nt][j]);
    if (lm == 0) {
#pragma unroll
        for (int j = 0; j < 4; ++j)
            ws_denp[((size_t)blk * 4 + h) * 16 + lq * 4 + j] = dacc[j];
    }
}

// ---------------- K2: reduce 16 tiles: out = 0.25*sum_h num/den + bias ------------------
__global__ __launch_bounds__(256) void k2_final(const unsigned short* __restrict__ ws_pvh,
                                                const float* __restrict__ ws_denp,
                                                const float* __restrict__ bias,
                                                float* __restrict__ out) {
    int b = blockIdx.x;                         // 128 = g(32) x rquad(4)
    int g = b >> 2;
    int r = (b & 3) * 4 + (threadIdx.x >> 6);   // wave-uniform -> den via s_loads
    int c = threadIdx.x & 63;
    float acc = 0.f;
#pragma unroll
    for (int h = 0; h < 4; ++h) {
        float num = 0.f, den = 0.f;
#pragma unroll
        for (int tl = 0; tl < 16; ++tl) {
            num += bf2f(ws_pvh[(((size_t)(g * 16 + tl)) * 4 + h) * 1024 + r * 64 + c]);
            den += ws_denp[((size_t)(g * 16 + tl) * 4 + h) * 16 + r];
        }
        acc += num / den;
    }
    out[(size_t)(g * 16 + r) * 64 + c] = fmaf(0.25f, acc, bias[c]);
}

extern "C" void kernel_launch(void* const* d_in, const int* in_sizes, int n_in,
                              void* d_out, int out_size, void* d_ws, size_t ws_size,
                              hipStream_t stream) {
    const float* x    = (const float*)d_in[0];
    const float* xcb  = (const float*)d_in[3];
    const float* W_l  = (const float*)d_in[4];
    const float* b_l  = (const float*)d_in[5];
    const float* W_r  = (const float*)d_in[6];
    const float* b_r  = (const float*)d_in[7];
    const float* att  = (const float*)d_in[8];
    const float* bias = (const float*)d_in[9];
    float* out = (float*)d_out;

    // workspace layout (~4.3 MB)
    unsigned short* ws_pvh = (unsigned short*)d_ws;       // 512 blk x 4 h x 16 r x 64 c bf16
    float* ws_denp = (float*)(ws_pvh + 2097152);          // 512 x 4 x 16 f32
    float* xrT     = ws_denp + 32768;                     // [hc][16r]
    float* xr_att6 = xrT + 4096;                          // 64
    float* att6    = xr_att6 + 64;                        // 256
    float* att4    = att6 + 256;                          // 256
    unsigned short* wt = (unsigned short*)(att4 + 256);   // 256x64 bf16

    k0_prep<<<17, 256, 0, stream>>>(xcb, W_l, W_r, b_r, att, xrT, xr_att6, att6, att4, wt, out);
    k1_fused<<<512, 256, 0, stream>>>(x, wt, b_l, att6, att4, xrT, xr_att6, ws_pvh, ws_denp);
    k2_final<<<128, 256, 0, stream>>>(ws_pvh, ws_denp, bias, out);
}

// Round 11
// 30.515 us; speedup vs baseline: 1.0700x; 1.0564x over previous
//
#include <hip/hip_runtime.h>

// BipartPool fused: GATv2 bipartite pooling, fully-regular structure.
// lrelu(z) = 0.6z + 0.4|z| -> logit = dot(xl,att6) + xr_att6[r,h] + sum_c |xl+xr|*att4
// No-max softmax (logits ~N(0,1), f32 exp safe): alpha = ex/den; den divided out in k2;
// PV runs on unnormalized ex; den comes free as a ones-column MFMA.
// This round: exact revert to the round-7 known-good source (29.9us, absmax 1e-3) plus
// TWO added barriers (C->D, D->E) that close the TBAA hazard (phase C writes xlT via
// uint2*, phase D reads via short*; without an IR fence the compiler may legally reorder
// -- this raced in R9). R9/R10's bundled changes (swizzle LDS, cvt_pk asm, restaged
// xr-in-LDS) introduced a deterministic absmax 0.56 that could not be attributed; all
// reverted. One change per round from here.

typedef __attribute__((ext_vector_type(8))) short short8;
typedef __attribute__((ext_vector_type(4))) float f32x4;

#define NPG 1024
#define NT 512

static __device__ __forceinline__ unsigned short f2bf(float f) {
    unsigned int u = __float_as_uint(f);
    u += 0x7fffu + ((u >> 16) & 1u);        // RNE (data is normal, no NaN handling)
    return (unsigned short)(u >> 16);
}
static __device__ __forceinline__ float bf2f(unsigned short u) {
    return __uint_as_float(((unsigned int)u) << 16);
}

// ---------------- K0: tables xrT[hc][16r], xr_att6, att6/att4, Wt bf16; batchcent --------
__global__ __launch_bounds__(256) void k0_prep(const float* __restrict__ xcb,
                                               const float* __restrict__ W_l,
                                               const float* __restrict__ W_r,
                                               const float* __restrict__ b_r,
                                               const float* __restrict__ att,
                                               float* __restrict__ xrT,
                                               float* __restrict__ xr_att6,
                                               float* __restrict__ att6,
                                               float* __restrict__ att4,
                                               unsigned short* __restrict__ wt,
                                               float* __restrict__ out) {
    int b = blockIdx.x, t = threadIdx.x;
    if (b < 16) {
        int r = b, hc = t;                  // one wave per head; W_r coalesced over hc
        float v = b_r[hc];
#pragma unroll
        for (int k = 0; k < 64; ++k)
            v = fmaf(xcb[r * 64 + k], W_r[k * 256 + hc], v);
        xrT[hc * 16 + r] = v;               // [hc][16r]: k1 s_loads 16-r rows per c
        float p = 0.6f * att[hc] * v;
        p += __shfl_xor(p, 1);  p += __shfl_xor(p, 2);
        p += __shfl_xor(p, 4);  p += __shfl_xor(p, 8);
        p += __shfl_xor(p, 16); p += __shfl_xor(p, 32);
        if ((t & 63) == 0) xr_att6[r * 4 + (t >> 6)] = p;
    } else {
        att6[t] = 0.6f * att[t];
        att4[t] = 0.4f * att[t];
        // Wt[c][k] = bf16(W_l[k][c])  (k-contiguous for MFMA B-frags)
        unsigned short tmp[64] __attribute__((aligned(16)));
#pragma unroll
        for (int k = 0; k < 64; ++k) tmp[k] = f2bf(W_l[k * 256 + t]);
#pragma unroll
        for (int q = 0; q < 8; ++q)
            *(short8*)(wt + t * 64 + q * 8) = *(const short8*)(tmp + q * 8);
        // batchcent: input-independent
        out[NT * 64 + t]       = (float)(t >> 4);
        out[NT * 64 + 256 + t] = (float)((256 + t) >> 4);
    }
}

// ---------------- K1: fused xl -> logits -> ex -> PV bf16 partials (wave = head) ---------
__global__ __launch_bounds__(256, 2) void k1_fused(const float* __restrict__ x,
                                                   const unsigned short* __restrict__ wt,
                                                   const float* __restrict__ b_l,
                                                   const float* __restrict__ att6,
                                                   const float* __restrict__ att4,
                                                   const float* __restrict__ xrT,
                                                   const float* __restrict__ xr_att6,
                                                   unsigned short* __restrict__ ws_pvh,
                                                   float* __restrict__ ws_denp) {
    __shared__ __align__(16) unsigned char smraw[(256 + 64) * 72 * 2];
    unsigned short (*As)[72]  = (unsigned short (*)[72])smraw;             // 64x72 (aliases xlT)
    unsigned short (*xlT)[72] = (unsigned short (*)[72])smraw;             // [h*64+c][n]
    unsigned short (*exT)[72] = (unsigned short (*)[72])(smraw + 256 * 72 * 2); // [h*16+r][n]

    const int t = threadIdx.x;
    const int blk = blockIdx.x;              // 512 tiles of 64 nodes
    const int n0 = blk * 64;

    // ---- phase A: stage x[64n][64k] f32 -> bf16 As ----
    {
        int n = t >> 2, q = (t & 3) * 16;
        const float* p = x + (size_t)(n0 + n) * 64 + q;
        float4 v0 = *(const float4*)p;
        float4 v1 = *(const float4*)(p + 4);
        float4 v2 = *(const float4*)(p + 8);
        float4 v3 = *(const float4*)(p + 12);
        unsigned short h16[16] __attribute__((aligned(16)));
        h16[0]=f2bf(v0.x); h16[1]=f2bf(v0.y); h16[2]=f2bf(v0.z); h16[3]=f2bf(v0.w);
        h16[4]=f2bf(v1.x); h16[5]=f2bf(v1.y); h16[6]=f2bf(v1.z); h16[7]=f2bf(v1.w);
        h16[8]=f2bf(v2.x); h16[9]=f2bf(v2.y); h16[10]=f2bf(v2.z); h16[11]=f2bf(v2.w);
        h16[12]=f2bf(v3.x); h16[13]=f2bf(v3.y); h16[14]=f2bf(v3.z); h16[15]=f2bf(v3.w);
        *(short8*)(&As[n][q])     = *(const short8*)h16;
        *(short8*)(&As[n][q + 8]) = *(const short8*)(h16 + 8);
    }
    __syncthreads();                         // barrier 1: staged tile visible

    const int l = t & 63;
    const int h = __builtin_amdgcn_readfirstlane(t >> 6);   // wave = head
    const int lm = l & 15, lq = l >> 4;
    const int lk = lq * 8;

    // ---- phase B: MFMA C[64n][64c] = x @ W_l(head h) ----
    short8 af[4][2], bfr[4][2];
#pragma unroll
    for (int mt = 0; mt < 4; ++mt)
#pragma unroll
        for (int ks = 0; ks < 2; ++ks)
            af[mt][ks] = *(const short8*)(&As[mt * 16 + lm][ks * 32 + lk]);
#pragma unroll
    for (int nt = 0; nt < 4; ++nt)
#pragma unroll
        for (int ks = 0; ks < 2; ++ks)
            bfr[nt][ks] = *(const short8*)(wt + (size_t)(h * 64 + nt * 16 + lm) * 64 + ks * 32 + lk);

    f32x4 acc[4][4];
#pragma unroll
    for (int mt = 0; mt < 4; ++mt)
#pragma unroll
        for (int nt = 0; nt < 4; ++nt) { f32x4 z = {0.f,0.f,0.f,0.f}; acc[mt][nt] = z; }
#pragma unroll
    for (int mt = 0; mt < 4; ++mt)
#pragma unroll
        for (int nt = 0; nt < 4; ++nt)
#pragma unroll
            for (int ks = 0; ks < 2; ++ks)
                acc[mt][nt] = __builtin_amdgcn_mfma_f32_16x16x32_bf16(
                    af[mt][ks], bfr[nt][ks], acc[mt][nt], 0, 0, 0);

    __syncthreads();   // barrier 2: all frag reads done; xlT may overwrite x tile

    // ---- phase C: acc(+b_l) -> xlT[h*64+c][n] bf16 ----
    // C layout: col(c) = lm (+nt*16), row(n) = lq*4 + j (+mt*16)   [m89-verified]
#pragma unroll
    for (int nt = 0; nt < 4; ++nt) {
        float bl = b_l[h * 64 + nt * 16 + lm];
#pragma unroll
        for (int mt = 0; mt < 4; ++mt) {
            unsigned int d0 = (unsigned int)f2bf(acc[mt][nt][0] + bl) |
                              ((unsigned int)f2bf(acc[mt][nt][1] + bl) << 16);
            unsigned int d1 = (unsigned int)f2bf(acc[mt][nt][2] + bl) |
                              ((unsigned int)f2bf(acc[mt][nt][3] + bl) << 16);
            *(uint2*)(&xlT[h * 64 + nt * 16 + lm][mt * 16 + lq * 4]) = make_uint2(d0, d1);
        }
    }
    __syncthreads();   // barrier 3 (added): fence uint2 stores vs phase-D short reads (TBAA)

    // ---- phase D: logits; xv from own rows; xr rows = wave-uniform s_load streams ----
    float base = 0.f;
    float lacc[16];
#pragma unroll
    for (int r = 0; r < 16; ++r) lacc[r] = 0.f;
#pragma unroll 4
    for (int c = 0; c < 64; ++c) {
        int row = h * 64 + c;
        float xv = bf2f(xlT[row][l]);
        base = fmaf(xv, att6[row], base);
        float a4 = att4[row];
        const float* xp = xrT + (size_t)row * 16;             // wave-uniform: s_loads
#pragma unroll
        for (int r = 0; r < 16; ++r)
            lacc[r] = fmaf(fabsf(xv + xp[r]), a4, lacc[r]);   // abs = free VOP3 modifier
    }
#pragma unroll
    for (int r = 0; r < 16; ++r) {
        float ex = __expf(base + lacc[r] + xr_att6[r * 4 + h]);   // no-max softmax
        exT[h * 16 + r][l] = f2bf(ex);
    }
    __syncthreads();   // barrier 4 (added): fence E scalar stores vs phase-E short8 reads

    // ---- phase E: PV MFMA: pacc[16r][64c] = ex^T @ xl ; ones-col B gives den ----
    short8 ap[2];
#pragma unroll
    for (int ks = 0; ks < 2; ++ks)
        ap[ks] = *(const short8*)(&exT[h * 16 + lm][ks * 32 + lk]);
    short o = (lm == 0) ? (short)0x3F80 : (short)0;   // bf16 1.0 in column 0
    short8 onesf = {o, o, o, o, o, o, o, o};

    f32x4 pacc[4], dacc;
    { f32x4 z = {0.f,0.f,0.f,0.f}; pacc[0]=z; pacc[1]=z; pacc[2]=z; pacc[3]=z; dacc=z; }
#pragma unroll
    for (int ks = 0; ks < 2; ++ks) {
#pragma unroll
        for (int nt = 0; nt < 4; ++nt) {
            short8 bp = *(const short8*)(&xlT[h * 64 + nt * 16 + lm][ks * 32 + lk]);
            pacc[nt] = __builtin_amdgcn_mfma_f32_16x16x32_bf16(ap[ks], bp, pacc[nt], 0, 0, 0);
        }
        dacc = __builtin_amdgcn_mfma_f32_16x16x32_bf16(ap[ks], onesf, dacc, 0, 0, 0);
    }

    // ---- store partials: pvh[blk][h][16r][64c] bf16, denp[blk][h][16r] f32 ----
    unsigned short* pvb = ws_pvh + ((size_t)blk * 4 + h) * 1024;
#pragma unroll
    for (int nt = 0; nt < 4; ++nt)
#pragma unroll
        for (int j = 0; j < 4; ++j)
            pvb[(lq * 4 + j) * 64 + nt * 16 + lm] = f2bf(pacc[nt][j]);
    if (lm == 0) {
#pragma unroll
        for (int j = 0; j < 4; ++j)
            ws_denp[((size_t)blk * 4 + h) * 16 + lq * 4 + j] = dacc[j];
    }
}

// ---------------- K2: reduce 16 tiles: out = 0.25*sum_h num/den + bias ------------------
__global__ __launch_bounds__(256) void k2_final(const unsigned short* __restrict__ ws_pvh,
                                                const float* __restrict__ ws_denp,
                                                const float* __restrict__ bias,
                                                float* __restrict__ out) {
    int b = blockIdx.x;                         // 128 = g(32) x rquad(4)
    int g = b >> 2;
    int r = (b & 3) * 4 + (threadIdx.x >> 6);   // wave-uniform -> den via s_loads
    int c = threadIdx.x & 63;
    float acc = 0.f;
#pragma unroll
    for (int h = 0; h < 4; ++h) {
        float num = 0.f, den = 0.f;
#pragma unroll
        for (int tl = 0; tl < 16; ++tl) {
            num += bf2f(ws_pvh[(((size_t)(g * 16 + tl)) * 4 + h) * 1024 + r * 64 + c]);
            den += ws_denp[((size_t)(g * 16 + tl) * 4 + h) * 16 + r];
        }
        acc += num / den;
    }
    out[(size_t)(g * 16 + r) * 64 + c] = fmaf(0.25f, acc, bias[c]);
}

extern "C" void kernel_launch(void* const* d_in, const int* in_sizes, int n_in,
                              void* d_out, int out_size, void* d_ws, size_t ws_size,
                              hipStream_t stream) {
    const float* x    = (const float*)d_in[0];
    const float* xcb  = (const float*)d_in[3];
    const float* W_l  = (const float*)d_in[4];
    const float* b_l  = (const float*)d_in[5];
    const float* W_r  = (const float*)d_in[6];
    const float* b_r  = (const float*)d_in[7];
    const float* att  = (const float*)d_in[8];
    const float* bias = (const float*)d_in[9];
    float* out = (float*)d_out;

    // workspace layout (~4.3 MB)
    unsigned short* ws_pvh = (unsigned short*)d_ws;       // 512 blk x 4 h x 16 r x 64 c bf16
    float* ws_denp = (float*)(ws_pvh + 2097152);          // 512 x 4 x 16 f32
    float* xrT     = ws_denp + 32768;                     // [hc][16r]
    float* xr_att6 = xrT + 4096;                          // 64
    float* att6    = xr_att6 + 64;                        // 256
    float* att4    = att6 + 256;                          // 256
    unsigned short* wt = (unsigned short*)(att4 + 256);   // 256x64 bf16

    k0_prep<<<17, 256, 0, stream>>>(xcb, W_l, W_r, b_r, att, xrT, xr_att6, att6, att4, wt, out);
    k1_fused<<<512, 256, 0, stream>>>(x, wt, b_l, att6, att4, xrT, xr_att6, ws_pvh, ws_denp);
    k2_final<<<128, 256, 0, stream>>>(ws_pvh, ws_denp, bias, out);
}